// Round 1
// baseline (292.162 us; speedup 1.0000x reference)
//
#include <hip/hip_runtime.h>
#include <stdint.h>

#define D 512
#define BATCH 8192
#define NMAP 1024
#define GRID_W 32
#define ALPHA 0.5f
#define C2 15.859712f   // 2*(35.2*0.08)^2

// ---------------- kernel: init packed argmin keys ----------------
__global__ void k_init(unsigned long long* packed) {
    int i = blockIdx.x * blockDim.x + threadIdx.x;
    packed[i] = 0xFFFFFFFFFFFFFFFFull;
}

// ---------------- kernel: m2[n] = ||map[n]||^2 ----------------
__global__ __launch_bounds__(64) void k_m2(const float* __restrict__ map,
                                           float* __restrict__ m2) {
    int n = blockIdx.x;
    int t = threadIdx.x;  // 64 threads = 1 wave
    const float* row = map + (size_t)n * D;
    float s = 0.f;
    #pragma unroll
    for (int k = 0; k < D / 64; k++) {
        float v = row[t + k * 64];
        s += v * v;
    }
    #pragma unroll
    for (int off = 32; off > 0; off >>= 1) s += __shfl_down(s, off);
    if (t == 0) m2[n] = s;
}

// ---------------- kernel: BMU search (fp32 GEMM + argmin epilogue) ----------
// C[b,n] = m2[n] - 2*dot(x[b],map[n])   (x2[b] constant per row: drop it)
// 64x64 tile per block, 256 threads, 4x4 per thread, K-step 16.
#define BT 64
#define NT 64
#define KT 16
#define LDP 20   // padded LDS row stride (floats); 80B keeps 16B alignment

__global__ __launch_bounds__(256) void k_bmu(const float* __restrict__ x,
                                             const float* __restrict__ map,
                                             const float* __restrict__ m2,
                                             unsigned long long* __restrict__ packed) {
    __shared__ float xs[BT][LDP];
    __shared__ float ms[NT][LDP];
    int b0 = blockIdx.x * BT;
    int n0 = blockIdx.y * NT;
    int t = threadIdx.x;
    int ty = t >> 4, tx = t & 15;
    int lrow = t >> 2;
    int lcol = (t & 3) << 2;
    const float* xg = x + (size_t)(b0 + lrow) * D + lcol;
    const float* mg = map + (size_t)(n0 + lrow) * D + lcol;

    float acc[4][4];
    #pragma unroll
    for (int i = 0; i < 4; i++)
        #pragma unroll
        for (int j = 0; j < 4; j++) acc[i][j] = 0.f;

    for (int k0 = 0; k0 < D; k0 += KT) {
        float4 xv = *(const float4*)(xg + k0);
        float4 mv = *(const float4*)(mg + k0);
        *(float4*)&xs[lrow][lcol] = xv;
        *(float4*)&ms[lrow][lcol] = mv;
        __syncthreads();
        #pragma unroll
        for (int kk = 0; kk < KT; kk += 4) {
            float4 a[4], bv[4];
            #pragma unroll
            for (int i = 0; i < 4; i++) a[i] = *(const float4*)&xs[ty * 4 + i][kk];
            #pragma unroll
            for (int j = 0; j < 4; j++) bv[j] = *(const float4*)&ms[tx * 4 + j][kk];
            #pragma unroll
            for (int i = 0; i < 4; i++)
                #pragma unroll
                for (int j = 0; j < 4; j++)
                    acc[i][j] += a[i].x * bv[j].x + a[i].y * bv[j].y +
                                 a[i].z * bv[j].z + a[i].w * bv[j].w;
        }
        __syncthreads();
    }

    float m2v[4];
    #pragma unroll
    for (int j = 0; j < 4; j++) m2v[j] = m2[n0 + tx * 4 + j];

    #pragma unroll
    for (int i = 0; i < 4; i++) {
        float bestv = 0.f;
        int besti = -1;
        #pragma unroll
        for (int j = 0; j < 4; j++) {
            int n = n0 + tx * 4 + j;
            float v = m2v[j] - 2.0f * acc[i][j];
            if (besti < 0 || v < bestv) { bestv = v; besti = n; }
        }
        // reduce across the 16 lanes (tx) sharing this row; lower n wins ties
        #pragma unroll
        for (int msk = 1; msk <= 8; msk <<= 1) {
            float ov = __shfl_xor(bestv, msk);
            int oi = __shfl_xor(besti, msk);
            if (ov < bestv || (ov == bestv && oi < besti)) { bestv = ov; besti = oi; }
        }
        if (tx == 0) {
            unsigned int fb = __float_as_uint(bestv);
            fb = (fb & 0x80000000u) ? ~fb : (fb | 0x80000000u);
            unsigned long long key =
                ((unsigned long long)fb << 32) | (unsigned int)besti;
            atomicMin(&packed[b0 + ty * 4 + i], key);
        }
    }
}

// ---------------- kernel: extract bmu index ----------------
__global__ void k_extract(const unsigned long long* __restrict__ packed,
                          int* __restrict__ bmu) {
    int i = blockIdx.x * blockDim.x + threadIdx.x;
    bmu[i] = (int)(packed[i] & 0xFFFFFFFFull);
}

// ---------------- kernel: deterministic scatter-sum ----------------
// S[g,d] = sum over {b : bmu[b]==g} of x[b,d], summed in ascending-b order.
__global__ __launch_bounds__(256) void k_scatter(const float* __restrict__ x,
                                                 const int* __restrict__ bmu,
                                                 float* __restrict__ S,
                                                 int* __restrict__ cnt) {
    __shared__ int list[BATCH];
    __shared__ int cnts[256];
    __shared__ int offs[256];
    int g = blockIdx.x;
    int t = threadIdx.x;
    int b0 = t * (BATCH / 256);  // 32 contiguous b's per thread

    int c = 0;
    for (int i = 0; i < BATCH / 256; i++) c += (bmu[b0 + i] == g) ? 1 : 0;
    cnts[t] = c;
    __syncthreads();
    if (t == 0) {
        int run = 0;
        for (int i = 0; i < 256; i++) { offs[i] = run; run += cnts[i]; }
    }
    __syncthreads();
    int off = offs[t];
    for (int i = 0; i < BATCH / 256; i++) {
        int b = b0 + i;
        if (bmu[b] == g) list[off++] = b;
    }
    __syncthreads();
    int len = offs[255] + cnts[255];

    float acc0 = 0.f, acc1 = 0.f;
    for (int i = 0; i < len; i++) {
        const float* xr = x + (size_t)list[i] * D;
        acc0 += xr[t];
        acc1 += xr[t + 256];
    }
    S[(size_t)g * D + t] = acc0;
    S[(size_t)g * D + t + 256] = acc1;
    if (t == 0) cnt[g] = len;
}

// ---------------- kernel: separable conv, axis j ----------------
// V[gi,nj,d] = sum_gj t[|nj-gj|] * S[gi*32+gj, d]
__global__ __launch_bounds__(256) void k_conv1(const float* __restrict__ S,
                                               float* __restrict__ V) {
    __shared__ float tbl[GRID_W];
    int gi = blockIdx.x;
    int d = blockIdx.y * 256 + threadIdx.x;
    if (threadIdx.x < GRID_W)
        tbl[threadIdx.x] = __expf(-(float)(threadIdx.x * threadIdx.x) / C2);
    __syncthreads();
    float acc[GRID_W];
    #pragma unroll
    for (int nj = 0; nj < GRID_W; nj++) acc[nj] = 0.f;
    for (int gj = 0; gj < GRID_W; gj++) {
        float s = S[(size_t)(gi * GRID_W + gj) * D + d];
        #pragma unroll
        for (int nj = 0; nj < GRID_W; nj++) {
            int dd = nj - gj; dd = dd < 0 ? -dd : dd;
            acc[nj] += tbl[dd] * s;
        }
    }
    #pragma unroll
    for (int nj = 0; nj < GRID_W; nj++)
        V[(size_t)(gi * GRID_W + nj) * D + d] = acc[nj];
}

// ---------------- kernel: sum_lr[n] (separable over counts) ----------------
__global__ __launch_bounds__(1024) void k_sumlr(const int* __restrict__ cnt,
                                                float* __restrict__ sum_lr) {
    __shared__ float tbl[GRID_W];
    __shared__ float vc[GRID_W][GRID_W];  // [gi][nj]
    int t = threadIdx.x;
    if (t < GRID_W) tbl[t] = __expf(-(float)(t * t) / C2);
    __syncthreads();
    int a = t >> 5, b = t & 31;  // (gi,nj) then (ni,nj)
    float s = 0.f;
    for (int gj = 0; gj < GRID_W; gj++) {
        int dd = gj - b; dd = dd < 0 ? -dd : dd;
        s += tbl[dd] * (float)cnt[a * GRID_W + gj];
    }
    vc[a][b] = s;
    __syncthreads();
    float s2 = 0.f;
    for (int gi = 0; gi < GRID_W; gi++) {
        int dd = gi - a; dd = dd < 0 ? -dd : dd;
        s2 += tbl[dd] * vc[gi][b];
    }
    sum_lr[t] = ALPHA * s2;
}

// ---------------- kernel: separable conv axis i + epilogue ----------------
// out[(ni*32+nj), d] = map*(1-sum_lr) + ALPHA * sum_gi t[|ni-gi|] * V[gi,nj,d]
__global__ __launch_bounds__(256) void k_conv2(const float* __restrict__ V,
                                               const float* __restrict__ map,
                                               const float* __restrict__ sum_lr,
                                               float* __restrict__ out) {
    __shared__ float tbl[GRID_W];
    int nj = blockIdx.x;
    int d = blockIdx.y * 256 + threadIdx.x;
    if (threadIdx.x < GRID_W)
        tbl[threadIdx.x] = __expf(-(float)(threadIdx.x * threadIdx.x) / C2);
    __syncthreads();
    float acc[GRID_W];
    #pragma unroll
    for (int ni = 0; ni < GRID_W; ni++) acc[ni] = 0.f;
    for (int gi = 0; gi < GRID_W; gi++) {
        float v = V[(size_t)(gi * GRID_W + nj) * D + d];
        #pragma unroll
        for (int ni = 0; ni < GRID_W; ni++) {
            int dd = ni - gi; dd = dd < 0 ? -dd : dd;
            acc[ni] += tbl[dd] * v;
        }
    }
    #pragma unroll
    for (int ni = 0; ni < GRID_W; ni++) {
        int n = ni * GRID_W + nj;
        out[(size_t)n * D + d] =
            map[(size_t)n * D + d] * (1.0f - sum_lr[n]) + ALPHA * acc[ni];
    }
}

// ---------------- launcher ----------------
extern "C" void kernel_launch(void* const* d_in, const int* in_sizes, int n_in,
                              void* d_out, int out_size, void* d_ws, size_t ws_size,
                              hipStream_t stream) {
    (void)in_sizes; (void)n_in; (void)out_size; (void)ws_size;
    const float* x = (const float*)d_in[0];
    const float* map = (const float*)d_in[1];
    // d_in[2] (locs) is exactly meshgrid(32,32): computed arithmetically.
    float* out = (float*)d_out;

    char* ws = (char*)d_ws;
    unsigned long long* packed = (unsigned long long*)(ws);        // 64 KB
    int* bmu = (int*)(ws + 65536);                                 // 32 KB
    float* m2 = (float*)(ws + 98304);                              // 4 KB
    int* cnt = (int*)(ws + 102400);                                // 4 KB
    float* sum_lr = (float*)(ws + 106496);                         // 4 KB
    float* S = (float*)(ws + 110592);                              // 2 MB
    float* V = (float*)(ws + 110592 + 2097152);                    // 2 MB

    k_init<<<BATCH / 256, 256, 0, stream>>>(packed);
    k_m2<<<NMAP, 64, 0, stream>>>(map, m2);
    k_bmu<<<dim3(BATCH / BT, NMAP / NT), 256, 0, stream>>>(x, map, m2, packed);
    k_extract<<<BATCH / 256, 256, 0, stream>>>(packed, bmu);
    k_scatter<<<NMAP, 256, 0, stream>>>(x, bmu, S, cnt);
    k_conv1<<<dim3(GRID_W, D / 256), 256, 0, stream>>>(S, V);
    k_sumlr<<<1, 1024, 0, stream>>>(cnt, sum_lr);
    k_conv2<<<dim3(GRID_W, D / 256), 256, 0, stream>>>(V, map, sum_lr, out);
}

// Round 2
// 122.289 us; speedup vs baseline: 2.3891x; 2.3891x over previous
//
#include <hip/hip_runtime.h>
#include <stdint.h>

#define D 512
#define KTOT 1536
#define BATCH 8192
#define NMAP 1024
#define GRID_W 32
#define ALPHA 0.5f
#define C2 15.859712f   // 2*(35.2*0.08)^2

typedef __attribute__((ext_vector_type(4))) float f32x4;
typedef __attribute__((ext_vector_type(8))) short bf16x8;
typedef __attribute__((ext_vector_type(8))) unsigned short u16x8;

static __device__ __forceinline__ unsigned short f2bf(float f) {
    uint32_t u = __float_as_uint(f);
    uint32_t r = (u + 0x7FFFu + ((u >> 16) & 1u)) >> 16;
    return (unsigned short)r;
}
static __device__ __forceinline__ float bf2f(unsigned short h) {
    return __uint_as_float(((uint32_t)h) << 16);
}

// ---------------- init packed argmin keys ----------------
__global__ void k_init(unsigned long long* packed) {
    int i = blockIdx.x * blockDim.x + threadIdx.x;
    packed[i] = 0xFFFFFFFFFFFFFFFFull;
}

// ---------------- m2[n] = ||map[n]||^2 (fp32) ----------------
__global__ __launch_bounds__(64) void k_m2(const float* __restrict__ map,
                                           float* __restrict__ m2) {
    int n = blockIdx.x;
    int t = threadIdx.x;
    const float* row = map + (size_t)n * D;
    float s = 0.f;
    #pragma unroll
    for (int k = 0; k < D / 64; k++) {
        float v = row[t + k * 64];
        s += v * v;
    }
    #pragma unroll
    for (int off = 32; off > 0; off >>= 1) s += __shfl_down(s, off);
    if (t == 0) m2[n] = s;
}

// ---------------- split x -> As = [xh | xl | xh] (bf16, K=1536) ------------
__global__ __launch_bounds__(256) void k_split_x(const float* __restrict__ x,
                                                 unsigned short* __restrict__ As) {
    int g = blockIdx.x * 256 + threadIdx.x;  // one thread per 8 elements
    int b = g >> 6;                          // 64 groups of 8 per row
    int k8 = (g & 63) << 3;
    const float* xp = x + (size_t)b * D + k8;
    float4 v0 = *(const float4*)xp;
    float4 v1 = *(const float4*)(xp + 4);
    float vv[8] = {v0.x, v0.y, v0.z, v0.w, v1.x, v1.y, v1.z, v1.w};
    u16x8 hi, lo;
    #pragma unroll
    for (int j = 0; j < 8; j++) {
        unsigned short h = f2bf(vv[j]);
        hi[j] = h;
        lo[j] = f2bf(vv[j] - bf2f(h));
    }
    unsigned short* row = As + (size_t)b * KTOT;
    *(u16x8*)(row + k8) = hi;
    *(u16x8*)(row + 512 + k8) = lo;
    *(u16x8*)(row + 1024 + k8) = hi;
}

// ---------------- split map -> Bs = [mh | mh | ml] (bf16, K=1536) ----------
__global__ __launch_bounds__(256) void k_split_m(const float* __restrict__ map,
                                                 unsigned short* __restrict__ Bs) {
    int g = blockIdx.x * 256 + threadIdx.x;
    int n = g >> 6;
    int k8 = (g & 63) << 3;
    const float* mp = map + (size_t)n * D + k8;
    float4 v0 = *(const float4*)mp;
    float4 v1 = *(const float4*)(mp + 4);
    float vv[8] = {v0.x, v0.y, v0.z, v0.w, v1.x, v1.y, v1.z, v1.w};
    u16x8 hi, lo;
    #pragma unroll
    for (int j = 0; j < 8; j++) {
        unsigned short h = f2bf(vv[j]);
        hi[j] = h;
        lo[j] = f2bf(vv[j] - bf2f(h));
    }
    unsigned short* row = Bs + (size_t)n * KTOT;
    *(u16x8*)(row + k8) = hi;
    *(u16x8*)(row + 512 + k8) = hi;
    *(u16x8*)(row + 1024 + k8) = lo;
}

// ---------------- BMU: bf16 MFMA GEMM + fused argmin ----------------
// dist[b,n] = m2[n] - 2*dot(x[b],map[n]); argmin_n per row b.
// 128x128 tile, BK=64, 4 waves (2x2), 64x64 per wave, 16x16x32 MFMA.
// LDS st-swizzle: slot' = slot ^ (row&7) (16B slots, 128B rows);
// global_load_lds keeps LDS linear, source address carries the inverse swizzle.
#define BM 128
#define BN 128
#define BK 64

__global__ __launch_bounds__(256) void k_bmu(const unsigned short* __restrict__ As,
                                             const unsigned short* __restrict__ Bs,
                                             const float* __restrict__ m2,
                                             unsigned long long* __restrict__ packed) {
    __shared__ unsigned short Al[BM * BK];  // 16 KB
    __shared__ unsigned short Bl[BN * BK];  // 16 KB
    const int b0 = blockIdx.x * BM;
    const int n0 = blockIdx.y * BN;
    const int t = threadIdx.x;
    const int w = t >> 6, l = t & 63;
    const int wm = w >> 1, wn = w & 1;

    f32x4 acc[4][4];
    #pragma unroll
    for (int i = 0; i < 4; i++)
        #pragma unroll
        for (int j = 0; j < 4; j++) acc[i][j] = (f32x4)(0.f);

    // staging geometry: wave w stages rows [w*32, w*32+32) of each tile,
    // 4 issues x 64 lanes x 16B. row = w*32 + i*8 + (l>>3); slot = l&7.
    const int srow = l >> 3;
    const int sslot = (l & 7) ^ (l >> 3);  // inverse-swizzled source slot
    const unsigned short* agp0 = As + (size_t)(b0 + w * 32 + srow) * KTOT + sslot * 8;
    const unsigned short* bgp0 = Bs + (size_t)(n0 + w * 32 + srow) * KTOT + sslot * 8;

    for (int kt = 0; kt < KTOT; kt += BK) {
        #pragma unroll
        for (int i = 0; i < 4; i++) {
            __builtin_amdgcn_global_load_lds(
                (const __attribute__((address_space(1))) void*)(agp0 + (size_t)i * 8 * KTOT + kt),
                (__attribute__((address_space(3))) void*)(Al + w * 2048 + i * 512), 16, 0, 0);
            __builtin_amdgcn_global_load_lds(
                (const __attribute__((address_space(1))) void*)(bgp0 + (size_t)i * 8 * KTOT + kt),
                (__attribute__((address_space(3))) void*)(Bl + w * 2048 + i * 512), 16, 0, 0);
        }
        __syncthreads();

        #pragma unroll
        for (int kk = 0; kk < 2; kk++) {
            bf16x8 af[4], bfr[4];
            #pragma unroll
            for (int mi = 0; mi < 4; mi++) {
                int r = wm * 64 + mi * 16 + (l & 15);
                int slot = kk * 4 + (l >> 4);
                af[mi] = *(const bf16x8*)&Al[r * 64 + ((slot ^ (r & 7)) << 3)];
            }
            #pragma unroll
            for (int nj = 0; nj < 4; nj++) {
                int r = wn * 64 + nj * 16 + (l & 15);
                int slot = kk * 4 + (l >> 4);
                bfr[nj] = *(const bf16x8*)&Bl[r * 64 + ((slot ^ (r & 7)) << 3)];
            }
            #pragma unroll
            for (int mi = 0; mi < 4; mi++)
                #pragma unroll
                for (int nj = 0; nj < 4; nj++)
                    acc[mi][nj] = __builtin_amdgcn_mfma_f32_16x16x32_bf16(
                        af[mi], bfr[nj], acc[mi][nj], 0, 0, 0);
        }
        __syncthreads();
    }

    // ---- fused argmin epilogue ----
    float m2v[4];
    #pragma unroll
    for (int nj = 0; nj < 4; nj++)
        m2v[nj] = m2[n0 + wn * 64 + nj * 16 + (l & 15)];

    #pragma unroll
    for (int mi = 0; mi < 4; mi++) {
        #pragma unroll
        for (int reg = 0; reg < 4; reg++) {
            float best = m2v[0] - 2.0f * acc[mi][0][reg];
            int bi = n0 + wn * 64 + (l & 15);
            #pragma unroll
            for (int nj = 1; nj < 4; nj++) {
                float v = m2v[nj] - 2.0f * acc[mi][nj][reg];
                int n = n0 + wn * 64 + nj * 16 + (l & 15);
                if (v < best) { best = v; bi = n; }
            }
            // reduce across the 16 lanes sharing this row (same l>>4 group)
            #pragma unroll
            for (int msk = 1; msk <= 8; msk <<= 1) {
                float ov = __shfl_xor(best, msk);
                int oi = __shfl_xor(bi, msk);
                if (ov < best || (ov == best && oi < bi)) { best = ov; bi = oi; }
            }
            if ((l & 15) == 0) {
                unsigned int fb = __float_as_uint(best);
                fb = (fb & 0x80000000u) ? ~fb : (fb | 0x80000000u);
                unsigned long long key =
                    ((unsigned long long)fb << 32) | (unsigned int)bi;
                int row = b0 + wm * 64 + mi * 16 + (l >> 4) * 4 + reg;
                atomicMin(&packed[row], key);
            }
        }
    }
}

// ---------------- extract bmu index ----------------
__global__ void k_extract(const unsigned long long* __restrict__ packed,
                          int* __restrict__ bmu) {
    int i = blockIdx.x * blockDim.x + threadIdx.x;
    bmu[i] = (int)(packed[i] & 0xFFFFFFFFull);
}

// ---------------- deterministic scatter-sum ----------------
__global__ __launch_bounds__(256) void k_scatter(const float* __restrict__ x,
                                                 const int* __restrict__ bmu,
                                                 float* __restrict__ S,
                                                 int* __restrict__ cnt) {
    __shared__ int list[BATCH];
    __shared__ int cnts[256];
    __shared__ int offs[256];
    int g = blockIdx.x;
    int t = threadIdx.x;
    int b0 = t * (BATCH / 256);

    int c = 0;
    for (int i = 0; i < BATCH / 256; i++) c += (bmu[b0 + i] == g) ? 1 : 0;
    cnts[t] = c;
    __syncthreads();
    if (t == 0) {
        int run = 0;
        for (int i = 0; i < 256; i++) { offs[i] = run; run += cnts[i]; }
    }
    __syncthreads();
    int off = offs[t];
    for (int i = 0; i < BATCH / 256; i++) {
        int b = b0 + i;
        if (bmu[b] == g) list[off++] = b;
    }
    __syncthreads();
    int len = offs[255] + cnts[255];

    float acc0 = 0.f, acc1 = 0.f;
    for (int i = 0; i < len; i++) {
        const float* xr = x + (size_t)list[i] * D;
        acc0 += xr[t];
        acc1 += xr[t + 256];
    }
    S[(size_t)g * D + t] = acc0;
    S[(size_t)g * D + t + 256] = acc1;
    if (t == 0) cnt[g] = len;
}

// ---------------- separable conv, axis j ----------------
__global__ __launch_bounds__(256) void k_conv1(const float* __restrict__ S,
                                               float* __restrict__ V) {
    __shared__ float tbl[GRID_W];
    int gi = blockIdx.x;
    int d = blockIdx.y * 256 + threadIdx.x;
    if (threadIdx.x < GRID_W)
        tbl[threadIdx.x] = __expf(-(float)(threadIdx.x * threadIdx.x) / C2);
    __syncthreads();
    float acc[GRID_W];
    #pragma unroll
    for (int nj = 0; nj < GRID_W; nj++) acc[nj] = 0.f;
    for (int gj = 0; gj < GRID_W; gj++) {
        float s = S[(size_t)(gi * GRID_W + gj) * D + d];
        #pragma unroll
        for (int nj = 0; nj < GRID_W; nj++) {
            int dd = nj - gj; dd = dd < 0 ? -dd : dd;
            acc[nj] += tbl[dd] * s;
        }
    }
    #pragma unroll
    for (int nj = 0; nj < GRID_W; nj++)
        V[(size_t)(gi * GRID_W + nj) * D + d] = acc[nj];
}

// ---------------- sum_lr[n] (separable over counts) ----------------
__global__ __launch_bounds__(1024) void k_sumlr(const int* __restrict__ cnt,
                                                float* __restrict__ sum_lr) {
    __shared__ float tbl[GRID_W];
    __shared__ float vc[GRID_W][GRID_W];
    int t = threadIdx.x;
    if (t < GRID_W) tbl[t] = __expf(-(float)(t * t) / C2);
    __syncthreads();
    int a = t >> 5, b = t & 31;
    float s = 0.f;
    for (int gj = 0; gj < GRID_W; gj++) {
        int dd = gj - b; dd = dd < 0 ? -dd : dd;
        s += tbl[dd] * (float)cnt[a * GRID_W + gj];
    }
    vc[a][b] = s;
    __syncthreads();
    float s2 = 0.f;
    for (int gi = 0; gi < GRID_W; gi++) {
        int dd = gi - a; dd = dd < 0 ? -dd : dd;
        s2 += tbl[dd] * vc[gi][b];
    }
    sum_lr[t] = ALPHA * s2;
}

// ---------------- separable conv axis i + epilogue ----------------
__global__ __launch_bounds__(256) void k_conv2(const float* __restrict__ V,
                                               const float* __restrict__ map,
                                               const float* __restrict__ sum_lr,
                                               float* __restrict__ out) {
    __shared__ float tbl[GRID_W];
    int nj = blockIdx.x;
    int d = blockIdx.y * 256 + threadIdx.x;
    if (threadIdx.x < GRID_W)
        tbl[threadIdx.x] = __expf(-(float)(threadIdx.x * threadIdx.x) / C2);
    __syncthreads();
    float acc[GRID_W];
    #pragma unroll
    for (int ni = 0; ni < GRID_W; ni++) acc[ni] = 0.f;
    for (int gi = 0; gi < GRID_W; gi++) {
        float v = V[(size_t)(gi * GRID_W + nj) * D + d];
        #pragma unroll
        for (int ni = 0; ni < GRID_W; ni++) {
            int dd = ni - gi; dd = dd < 0 ? -dd : dd;
            acc[ni] += tbl[dd] * v;
        }
    }
    #pragma unroll
    for (int ni = 0; ni < GRID_W; ni++) {
        int n = ni * GRID_W + nj;
        out[(size_t)n * D + d] =
            map[(size_t)n * D + d] * (1.0f - sum_lr[n]) + ALPHA * acc[ni];
    }
}

// ---------------- launcher ----------------
extern "C" void kernel_launch(void* const* d_in, const int* in_sizes, int n_in,
                              void* d_out, int out_size, void* d_ws, size_t ws_size,
                              hipStream_t stream) {
    (void)in_sizes; (void)n_in; (void)out_size; (void)ws_size;
    const float* x = (const float*)d_in[0];
    const float* map = (const float*)d_in[1];
    float* out = (float*)d_out;

    char* ws = (char*)d_ws;
    unsigned long long* packed = (unsigned long long*)(ws);        // 64 KB
    int* bmu = (int*)(ws + 65536);                                 // 32 KB
    float* m2 = (float*)(ws + 98304);                              // 4 KB
    int* cnt = (int*)(ws + 102400);                                // 4 KB
    float* sum_lr = (float*)(ws + 106496);                         // 4 KB
    float* S = (float*)(ws + 110592);                              // 2 MB
    float* V = (float*)(ws + 110592 + 2097152);                    // 2 MB
    unsigned short* As = (unsigned short*)(ws + 4304896);          // 24 MB
    unsigned short* Bs = (unsigned short*)(ws + 4304896 + 25165824); // 3 MB

    k_init<<<BATCH / 256, 256, 0, stream>>>(packed);
    k_m2<<<NMAP, 64, 0, stream>>>(map, m2);
    k_split_x<<<BATCH * (D / 8) / 256, 256, 0, stream>>>(x, As);
    k_split_m<<<NMAP * (D / 8) / 256, 256, 0, stream>>>(map, Bs);
    k_bmu<<<dim3(BATCH / BM, NMAP / BN), 256, 0, stream>>>(As, Bs, m2, packed);
    k_extract<<<BATCH / 256, 256, 0, stream>>>(packed, bmu);
    k_scatter<<<NMAP, 256, 0, stream>>>(x, bmu, S, cnt);
    k_conv1<<<dim3(GRID_W, D / 256), 256, 0, stream>>>(S, V);
    k_sumlr<<<1, 1024, 0, stream>>>(cnt, sum_lr);
    k_conv2<<<dim3(GRID_W, D / 256), 256, 0, stream>>>(V, map, sum_lr, out);
}

// Round 3
// 99.431 us; speedup vs baseline: 2.9383x; 1.2299x over previous
//
#include <hip/hip_runtime.h>
#include <stdint.h>

#define D 512
#define KTOT 1024       // [hi | lo] split, correction term xl*mh
#define BATCH 8192
#define NMAP 1024
#define GRID_W 32
#define ALPHA 0.5f
#define C2 15.859712f   // 2*(35.2*0.08)^2

typedef __attribute__((ext_vector_type(4))) float f32x4;
typedef __attribute__((ext_vector_type(8))) short bf16x8;
typedef __attribute__((ext_vector_type(8))) unsigned short u16x8;

static __device__ __forceinline__ unsigned short f2bf(float f) {
    uint32_t u = __float_as_uint(f);
    uint32_t r = (u + 0x7FFFu + ((u >> 16) & 1u)) >> 16;
    return (unsigned short)r;
}
static __device__ __forceinline__ float bf2f(unsigned short h) {
    return __uint_as_float(((uint32_t)h) << 16);
}

// ---------------- split x -> As = [xh | xl]  + init packed ----------------
__global__ __launch_bounds__(256) void k_split_x(const float* __restrict__ x,
                                                 unsigned short* __restrict__ As,
                                                 unsigned long long* __restrict__ packed) {
    int g = blockIdx.x * 256 + threadIdx.x;   // one thread per 8 elements
    if (g < BATCH) packed[g] = 0xFFFFFFFFFFFFFFFFull;
    int b = g >> 6;
    int k8 = (g & 63) << 3;
    const float* xp = x + (size_t)b * D + k8;
    float4 v0 = *(const float4*)xp;
    float4 v1 = *(const float4*)(xp + 4);
    float vv[8] = {v0.x, v0.y, v0.z, v0.w, v1.x, v1.y, v1.z, v1.w};
    u16x8 hi, lo;
    #pragma unroll
    for (int j = 0; j < 8; j++) {
        unsigned short h = f2bf(vv[j]);
        hi[j] = h;
        lo[j] = f2bf(vv[j] - bf2f(h));
    }
    unsigned short* row = As + (size_t)b * KTOT;
    *(u16x8*)(row + k8) = hi;
    *(u16x8*)(row + 512 + k8) = lo;
}

// ---------------- split map -> Bs = [mh | mh]  + m2 ----------------
// One wave per map row: 64 lanes x 8 elems = 512. Block = 4 rows.
__global__ __launch_bounds__(256) void k_split_m(const float* __restrict__ map,
                                                 unsigned short* __restrict__ Bs,
                                                 float* __restrict__ m2) {
    int n = blockIdx.x * 4 + (threadIdx.x >> 6);
    int lane = threadIdx.x & 63;
    const float* mp = map + (size_t)n * D + lane * 8;
    float4 v0 = *(const float4*)mp;
    float4 v1 = *(const float4*)(mp + 4);
    float vv[8] = {v0.x, v0.y, v0.z, v0.w, v1.x, v1.y, v1.z, v1.w};
    u16x8 hi;
    float s = 0.f;
    #pragma unroll
    for (int j = 0; j < 8; j++) {
        s += vv[j] * vv[j];
        hi[j] = f2bf(vv[j]);
    }
    unsigned short* row = Bs + (size_t)n * KTOT;
    *(u16x8*)(row + lane * 8) = hi;
    *(u16x8*)(row + 512 + lane * 8) = hi;
    #pragma unroll
    for (int off = 32; off > 0; off >>= 1) s += __shfl_down(s, off);
    if (lane == 0) m2[n] = s;
}

// ---------------- BMU: bf16 MFMA GEMM + fused argmin ----------------
// dist[b,n] = m2[n] - 2*(xh.mh + xl.mh); argmin_n per row b.
// 128x128 tile, BK=64, 4 waves (2x2), 16x16x32 MFMA, st-swizzled LDS.
#define BM 128
#define BN 128
#define BK 64

__global__ __launch_bounds__(256) void k_bmu(const unsigned short* __restrict__ As,
                                             const unsigned short* __restrict__ Bs,
                                             const float* __restrict__ m2,
                                             unsigned long long* __restrict__ packed) {
    __shared__ unsigned short Al[BM * BK];  // 16 KB
    __shared__ unsigned short Bl[BN * BK];  // 16 KB
    const int b0 = blockIdx.x * BM;
    const int n0 = blockIdx.y * BN;
    const int t = threadIdx.x;
    const int w = t >> 6, l = t & 63;
    const int wm = w >> 1, wn = w & 1;

    f32x4 acc[4][4];
    #pragma unroll
    for (int i = 0; i < 4; i++)
        #pragma unroll
        for (int j = 0; j < 4; j++) acc[i][j] = (f32x4)(0.f);

    // wave w stages rows [w*32, w*32+32): 4 issues x 64 lanes x 16B.
    // LDS linear; source carries the inverse st-swizzle (slot ^ row&7).
    const int srow = l >> 3;
    const int sslot = (l & 7) ^ (l >> 3);
    const unsigned short* agp0 = As + (size_t)(b0 + w * 32 + srow) * KTOT + sslot * 8;
    const unsigned short* bgp0 = Bs + (size_t)(n0 + w * 32 + srow) * KTOT + sslot * 8;

    for (int kt = 0; kt < KTOT; kt += BK) {
        #pragma unroll
        for (int i = 0; i < 4; i++) {
            __builtin_amdgcn_global_load_lds(
                (const __attribute__((address_space(1))) void*)(agp0 + (size_t)i * 8 * KTOT + kt),
                (__attribute__((address_space(3))) void*)(Al + w * 2048 + i * 512), 16, 0, 0);
            __builtin_amdgcn_global_load_lds(
                (const __attribute__((address_space(1))) void*)(bgp0 + (size_t)i * 8 * KTOT + kt),
                (__attribute__((address_space(3))) void*)(Bl + w * 2048 + i * 512), 16, 0, 0);
        }
        __syncthreads();

        #pragma unroll
        for (int kk = 0; kk < 2; kk++) {
            bf16x8 af[4], bfr[4];
            #pragma unroll
            for (int mi = 0; mi < 4; mi++) {
                int r = wm * 64 + mi * 16 + (l & 15);
                int slot = kk * 4 + (l >> 4);
                af[mi] = *(const bf16x8*)&Al[r * 64 + ((slot ^ (r & 7)) << 3)];
            }
            #pragma unroll
            for (int nj = 0; nj < 4; nj++) {
                int r = wn * 64 + nj * 16 + (l & 15);
                int slot = kk * 4 + (l >> 4);
                bfr[nj] = *(const bf16x8*)&Bl[r * 64 + ((slot ^ (r & 7)) << 3)];
            }
            #pragma unroll
            for (int mi = 0; mi < 4; mi++)
                #pragma unroll
                for (int nj = 0; nj < 4; nj++)
                    acc[mi][nj] = __builtin_amdgcn_mfma_f32_16x16x32_bf16(
                        af[mi], bfr[nj], acc[mi][nj], 0, 0, 0);
        }
        __syncthreads();
    }

    // ---- fused argmin epilogue ----
    float m2v[4];
    #pragma unroll
    for (int nj = 0; nj < 4; nj++)
        m2v[nj] = m2[n0 + wn * 64 + nj * 16 + (l & 15)];

    #pragma unroll
    for (int mi = 0; mi < 4; mi++) {
        #pragma unroll
        for (int reg = 0; reg < 4; reg++) {
            float best = m2v[0] - 2.0f * acc[mi][0][reg];
            int bi = n0 + wn * 64 + (l & 15);
            #pragma unroll
            for (int nj = 1; nj < 4; nj++) {
                float v = m2v[nj] - 2.0f * acc[mi][nj][reg];
                int n = n0 + wn * 64 + nj * 16 + (l & 15);
                if (v < best) { best = v; bi = n; }
            }
            #pragma unroll
            for (int msk = 1; msk <= 8; msk <<= 1) {
                float ov = __shfl_xor(best, msk);
                int oi = __shfl_xor(bi, msk);
                if (ov < best || (ov == best && oi < bi)) { best = ov; bi = oi; }
            }
            if ((l & 15) == 0) {
                unsigned int fb = __float_as_uint(best);
                fb = (fb & 0x80000000u) ? ~fb : (fb | 0x80000000u);
                unsigned long long key =
                    ((unsigned long long)fb << 32) | (unsigned int)bi;
                int row = b0 + wm * 64 + mi * 16 + (l >> 4) * 4 + reg;
                atomicMin(&packed[row], key);
            }
        }
    }
}

// ---------------- deterministic scatter-sum (reads packed directly) --------
__global__ __launch_bounds__(256) void k_scatter(const float* __restrict__ x,
                                                 const unsigned long long* __restrict__ packed,
                                                 float* __restrict__ S,
                                                 int* __restrict__ cnt) {
    __shared__ int list[BATCH];
    __shared__ int cnts[256];
    __shared__ int offs[256];
    int g = blockIdx.x;
    int t = threadIdx.x;
    int b0 = t * (BATCH / 256);

    int mybmu[BATCH / 256];
    int c = 0;
    #pragma unroll
    for (int i = 0; i < BATCH / 256; i++) {
        mybmu[i] = (int)(packed[b0 + i] & 0xFFFFFFFFull);
        c += (mybmu[i] == g) ? 1 : 0;
    }
    cnts[t] = c;
    offs[t] = c;
    __syncthreads();
    // Hillis-Steele inclusive scan over 256 entries
    #pragma unroll
    for (int s = 1; s < 256; s <<= 1) {
        int v = (t >= s) ? offs[t - s] : 0;
        __syncthreads();
        offs[t] += v;
        __syncthreads();
    }
    int off = offs[t] - cnts[t];  // exclusive
    #pragma unroll
    for (int i = 0; i < BATCH / 256; i++) {
        if (mybmu[i] == g) list[off++] = b0 + i;
    }
    __syncthreads();
    int len = offs[255];

    float acc0 = 0.f, acc1 = 0.f;
    for (int i = 0; i < len; i++) {
        const float* xr = x + (size_t)list[i] * D;
        acc0 += xr[t];
        acc1 += xr[t + 256];
    }
    S[(size_t)g * D + t] = acc0;
    S[(size_t)g * D + t + 256] = acc1;
    if (t == 0) cnt[g] = len;
}

// ---------------- separable conv axis j (+ sum_lr in block (0,0)) ----------
__global__ __launch_bounds__(256) void k_conv1(const float* __restrict__ S,
                                               float* __restrict__ V,
                                               const int* __restrict__ cnt,
                                               float* __restrict__ sum_lr) {
    __shared__ float tbl[GRID_W];
    __shared__ float vc[GRID_W][GRID_W];
    int gi = blockIdx.x;
    int d = blockIdx.y * 256 + threadIdx.x;
    if (threadIdx.x < GRID_W)
        tbl[threadIdx.x] = __expf(-(float)(threadIdx.x * threadIdx.x) / C2);
    __syncthreads();
    float acc[GRID_W];
    #pragma unroll
    for (int nj = 0; nj < GRID_W; nj++) acc[nj] = 0.f;
    for (int gj = 0; gj < GRID_W; gj++) {
        float s = S[(size_t)(gi * GRID_W + gj) * D + d];
        #pragma unroll
        for (int nj = 0; nj < GRID_W; nj++) {
            int dd = nj - gj; dd = dd < 0 ? -dd : dd;
            acc[nj] += tbl[dd] * s;
        }
    }
    #pragma unroll
    for (int nj = 0; nj < GRID_W; nj++)
        V[(size_t)(gi * GRID_W + nj) * D + d] = acc[nj];

    // ---- sum_lr (separable over counts), one block does it all ----
    if (blockIdx.x == 0 && blockIdx.y == 0) {
        int t = threadIdx.x;
        #pragma unroll
        for (int j = 0; j < 4; j++) {
            int idx = t * 4 + j;
            int a = idx >> 5, b = idx & 31;
            float s = 0.f;
            for (int gj = 0; gj < GRID_W; gj++) {
                int dd = gj - b; dd = dd < 0 ? -dd : dd;
                s += tbl[dd] * (float)cnt[a * GRID_W + gj];
            }
            vc[a][b] = s;
        }
        __syncthreads();
        #pragma unroll
        for (int j = 0; j < 4; j++) {
            int idx = t * 4 + j;
            int a = idx >> 5, b = idx & 31;
            float s2 = 0.f;
            for (int gg = 0; gg < GRID_W; gg++) {
                int dd = gg - a; dd = dd < 0 ? -dd : dd;
                s2 += tbl[dd] * vc[gg][b];
            }
            sum_lr[idx] = ALPHA * s2;
        }
    }
}

// ---------------- separable conv axis i + epilogue ----------------
__global__ __launch_bounds__(256) void k_conv2(const float* __restrict__ V,
                                               const float* __restrict__ map,
                                               const float* __restrict__ sum_lr,
                                               float* __restrict__ out) {
    __shared__ float tbl[GRID_W];
    int nj = blockIdx.x;
    int d = blockIdx.y * 256 + threadIdx.x;
    if (threadIdx.x < GRID_W)
        tbl[threadIdx.x] = __expf(-(float)(threadIdx.x * threadIdx.x) / C2);
    __syncthreads();
    float acc[GRID_W];
    #pragma unroll
    for (int ni = 0; ni < GRID_W; ni++) acc[ni] = 0.f;
    for (int gi = 0; gi < GRID_W; gi++) {
        float v = V[(size_t)(gi * GRID_W + nj) * D + d];
        #pragma unroll
        for (int ni = 0; ni < GRID_W; ni++) {
            int dd = ni - gi; dd = dd < 0 ? -dd : dd;
            acc[ni] += tbl[dd] * v;
        }
    }
    #pragma unroll
    for (int ni = 0; ni < GRID_W; ni++) {
        int n = ni * GRID_W + nj;
        out[(size_t)n * D + d] =
            map[(size_t)n * D + d] * (1.0f - sum_lr[n]) + ALPHA * acc[ni];
    }
}

// ---------------- launcher ----------------
extern "C" void kernel_launch(void* const* d_in, const int* in_sizes, int n_in,
                              void* d_out, int out_size, void* d_ws, size_t ws_size,
                              hipStream_t stream) {
    (void)in_sizes; (void)n_in; (void)out_size; (void)ws_size;
    const float* x = (const float*)d_in[0];
    const float* map = (const float*)d_in[1];
    float* out = (float*)d_out;

    char* ws = (char*)d_ws;
    unsigned long long* packed = (unsigned long long*)(ws);          // 64 KB
    float* m2 = (float*)(ws + 65536);                                // 4 KB
    int* cnt = (int*)(ws + 69632);                                   // 4 KB
    float* sum_lr = (float*)(ws + 73728);                            // 4 KB
    float* S = (float*)(ws + 77824);                                 // 2 MB
    float* V = (float*)(ws + 2175, 0 /*dummy*/);                     // (set below)
    V = (float*)(ws + 2174976);                                      // 2 MB
    unsigned short* As = (unsigned short*)(ws + 4272128);            // 16 MB
    unsigned short* Bs = (unsigned short*)(ws + 21049344);           // 2 MB

    k_split_x<<<BATCH * (D / 8) / 256, 256, 0, stream>>>(x, As, packed);
    k_split_m<<<NMAP / 4, 256, 0, stream>>>(map, Bs, m2);
    k_bmu<<<dim3(BATCH / BM, NMAP / BN), 256, 0, stream>>>(As, Bs, m2, packed);
    k_scatter<<<NMAP, 256, 0, stream>>>(x, packed, S, cnt);
    k_conv1<<<dim3(GRID_W, D / 256), 256, 0, stream>>>(S, V, cnt, sum_lr);
    k_conv2<<<dim3(GRID_W, D / 256), 256, 0, stream>>>(V, map, sum_lr, out);
}